// Round 1
// baseline (676.539 us; speedup 1.0000x reference)
//
#include <hip/hip_runtime.h>
#include <hip/hip_bf16.h>
#include <math.h>

typedef __bf16 bf16;
typedef __bf16 bf16x8 __attribute__((ext_vector_type(8)));
typedef float f32x4 __attribute__((ext_vector_type(4)));

#define NHEADS 6
#define CDIM 192
#define IMG 56
#define WINSZ 7
#define NTOK 49
#define SHIFTV 3
#define XSTR 200   // padded row stride (bf16 elems) for X/Q/K/O: 400 B, 2-way-free banks
#define VSTR 72    // padded stride for VT / P scratch: 144 B
#define SCALE 0.17677669529663687f

// ---- weight prep: fp32 -> bf16, transposed to [N][K] so B-fragments are contiguous ----
__global__ void prep_weights(const float* __restrict__ w_qkv, const float* __restrict__ w_proj,
                             bf16* __restrict__ wqkvT, bf16* __restrict__ wprojT) {
    int i = blockIdx.x * 256 + threadIdx.x;
    if (i < 576 * 192) {
        int n = i / 192, k = i % 192;
        wqkvT[i] = (bf16)w_qkv[k * 576 + n];
    }
    if (i < 192 * 192) {
        int n = i / 192, k = i % 192;
        wprojT[i] = (bf16)w_proj[k * 192 + n];
    }
}

__global__ __launch_bounds__(256, 1) void swin_block(
    const float* __restrict__ x, const float* __restrict__ gamma, const float* __restrict__ beta,
    const bf16* __restrict__ wqkvT, const float* __restrict__ b_qkv,
    const float* __restrict__ rel_table, const bf16* __restrict__ wprojT,
    const float* __restrict__ b_proj, const float* __restrict__ mask_matrix,
    float* __restrict__ out)
{
    __shared__ __align__(16) bf16 XO[64 * XSTR];       // X (phases 0-1), then O (phases 2-3)
    __shared__ __align__(16) bf16 Qs[64 * XSTR];
    __shared__ __align__(16) bf16 Ks[64 * XSTR];
    __shared__ __align__(16) bf16 VTs[CDIM * VSTR];    // V transposed: [channel][token]
    __shared__ __align__(16) bf16 Pws[4 * 16 * VSTR];  // per-wave P scratch
    __shared__ float maskS[NTOK * NTOK];
    __shared__ float biasS[169 * NHEADS];

    const int blk  = blockIdx.x;
    const int bimg = blk >> 6;
    const int wy   = (blk >> 3) & 7;
    const int wx   = blk & 7;
    const int widx = blk & 63;
    const int tid  = threadIdx.x;
    const int wave = tid >> 6;
    const int lane = tid & 63;

    // stage shift-mask (this window) and rel-pos table
    for (int i = tid; i < NTOK * NTOK; i += 256) maskS[i] = mask_matrix[widx * NTOK * NTOK + i];
    for (int i = tid; i < 169 * NHEADS; i += 256) biasS[i] = rel_table[i];

    // ---- phase 0: shifted-window load + LayerNorm -> XO (bf16), rows 49..63 zero ----
    {
        const float g0 = gamma[lane], g1 = gamma[lane + 64], g2 = gamma[lane + 128];
        const float b0 = beta[lane],  b1 = beta[lane + 64],  b2 = beta[lane + 128];
        for (int t = wave; t < 64; t += 4) {
            if (t < NTOK) {
                int ty = t / 7, tx = t % 7;
                int oy = (wy * 7 + ty + SHIFTV) % IMG;
                int ox = (wx * 7 + tx + SHIFTV) % IMG;
                const float* xp = x + (((size_t)bimg * IMG + oy) * IMG + ox) * CDIM;
                float v0 = xp[lane], v1 = xp[lane + 64], v2 = xp[lane + 128];
                float s = v0 + v1 + v2, ss = v0 * v0 + v1 * v1 + v2 * v2;
                #pragma unroll
                for (int off = 32; off; off >>= 1) { s += __shfl_xor(s, off); ss += __shfl_xor(ss, off); }
                float mu  = s * (1.f / 192.f);
                float var = ss * (1.f / 192.f) - mu * mu;
                float rs  = rsqrtf(var + 1e-5f);
                XO[t * XSTR + lane      ] = (bf16)((v0 - mu) * rs * g0 + b0);
                XO[t * XSTR + lane + 64 ] = (bf16)((v1 - mu) * rs * g1 + b1);
                XO[t * XSTR + lane + 128] = (bf16)((v2 - mu) * rs * g2 + b2);
            } else {
                XO[t * XSTR + lane      ] = (bf16)0.f;
                XO[t * XSTR + lane + 64 ] = (bf16)0.f;
                XO[t * XSTR + lane + 128] = (bf16)0.f;
            }
        }
    }
    __syncthreads();

    // ---- phase 1: QKV = X @ Wqkv + b -> Qs, Ks, VTs ----
    {
        const int lr = lane & 15, lq = lane >> 4;
        bf16x8 afrag[4][6];
        #pragma unroll
        for (int m = 0; m < 4; ++m)
            #pragma unroll
            for (int k = 0; k < 6; ++k)
                afrag[m][k] = *(const bf16x8*)&XO[(16 * m + lr) * XSTR + k * 32 + lq * 8];

        for (int nt = wave; nt < 36; nt += 4) {
            const bf16* wp = wqkvT + (size_t)(nt * 16 + lr) * CDIM + lq * 8;
            bf16x8 bfrag[6];
            #pragma unroll
            for (int k = 0; k < 6; ++k) bfrag[k] = *(const bf16x8*)(wp + k * 32);
            f32x4 acc[4];
            #pragma unroll
            for (int m = 0; m < 4; ++m) acc[m] = f32x4{0.f, 0.f, 0.f, 0.f};
            #pragma unroll
            for (int k = 0; k < 6; ++k)
                #pragma unroll
                for (int m = 0; m < 4; ++m)
                    acc[m] = __builtin_amdgcn_mfma_f32_16x16x32_bf16(afrag[m][k], bfrag[k], acc[m], 0, 0, 0);
            const int col  = nt * 16 + lr;
            const float bb = b_qkv[col];
            const int sect = col / CDIM;   // tile-uniform: 0=Q 1=K 2=V
            const int cc   = col % CDIM;
            #pragma unroll
            for (int m = 0; m < 4; ++m)
                #pragma unroll
                for (int r = 0; r < 4; ++r) {
                    int row = 16 * m + lq * 4 + r;
                    float v = acc[m][r] + bb;
                    if (sect == 0)      Qs[row * XSTR + cc] = (bf16)v;
                    else if (sect == 1) Ks[row * XSTR + cc] = (bf16)v;
                    else                VTs[cc * VSTR + row] = (bf16)v;
                }
        }
    }
    __syncthreads();

    // ---- phase 2: attention; wave w owns row-tile m=w for all heads ----
    {
        const int lr = lane & 15, lq = lane >> 4;
        const int m = wave;
        bf16* Pw = &Pws[wave * 16 * VSTR];
        for (int h = 0; h < NHEADS; ++h) {
            bf16x8 aq = *(const bf16x8*)&Qs[(16 * m + lr) * XSTR + h * 32 + lq * 8];
            f32x4 s[4];
            #pragma unroll
            for (int n = 0; n < 4; ++n) {
                bf16x8 bk = *(const bf16x8*)&Ks[(16 * n + lr) * XSTR + h * 32 + lq * 8];
                s[n] = __builtin_amdgcn_mfma_f32_16x16x32_bf16(aq, bk, f32x4{0.f, 0.f, 0.f, 0.f}, 0, 0, 0);
            }
            float p[4][4];
            #pragma unroll
            for (int r = 0; r < 4; ++r) {
                int i  = 16 * m + lq * 4 + r;
                int ic = i < NTOK ? i : NTOK - 1;
                int iy = ic / 7, ix = ic % 7;
                float vmax = -1e30f;
                #pragma unroll
                for (int n = 0; n < 4; ++n) {
                    int j = 16 * n + lr;
                    float v;
                    if (j < NTOK) {
                        int jy = j / 7, jx = j % 7;
                        int rp = (iy - jy + 6) * 13 + (ix - jx + 6);
                        v = s[n][r] * SCALE + biasS[rp * NHEADS + h] + maskS[ic * NTOK + j];
                    } else v = -1e30f;
                    p[r][n] = v;
                    vmax = fmaxf(vmax, v);
                }
                #pragma unroll
                for (int off = 1; off < 16; off <<= 1) vmax = fmaxf(vmax, __shfl_xor(vmax, off));
                float sum = 0.f;
                #pragma unroll
                for (int n = 0; n < 4; ++n) {
                    int j = 16 * n + lr;
                    float e = (j < NTOK) ? __expf(p[r][n] - vmax) : 0.f;
                    p[r][n] = e; sum += e;
                }
                #pragma unroll
                for (int off = 1; off < 16; off <<= 1) sum += __shfl_xor(sum, off);
                float inv = 1.f / sum;
                #pragma unroll
                for (int n = 0; n < 4; ++n) p[r][n] *= inv;
            }
            // D-layout -> A-layout via per-wave LDS scratch
            #pragma unroll
            for (int r = 0; r < 4; ++r)
                #pragma unroll
                for (int n = 0; n < 4; ++n)
                    Pw[(lq * 4 + r) * VSTR + 16 * n + lr] = (bf16)p[r][n];
            __syncthreads();
            // PV
            f32x4 o[2];
            o[0] = f32x4{0.f, 0.f, 0.f, 0.f}; o[1] = f32x4{0.f, 0.f, 0.f, 0.f};
            #pragma unroll
            for (int kk = 0; kk < 2; ++kk) {
                bf16x8 ap = *(const bf16x8*)&Pw[lr * VSTR + kk * 32 + lq * 8];
                #pragma unroll
                for (int n = 0; n < 2; ++n) {
                    bf16x8 bv = *(const bf16x8*)&VTs[(h * 32 + 16 * n + lr) * VSTR + kk * 32 + lq * 8];
                    o[n] = __builtin_amdgcn_mfma_f32_16x16x32_bf16(ap, bv, o[n], 0, 0, 0);
                }
            }
            #pragma unroll
            for (int n = 0; n < 2; ++n)
                #pragma unroll
                for (int r = 0; r < 4; ++r)
                    XO[(16 * m + lq * 4 + r) * XSTR + h * 32 + 16 * n + lr] = (bf16)o[n][r];
            __syncthreads();
        }
    }
    __syncthreads();

    // ---- phase 3: proj + bias, store with window-reverse + unshift ----
    {
        const int lr = lane & 15, lq = lane >> 4;
        bf16x8 ofrag[4][6];
        #pragma unroll
        for (int m = 0; m < 4; ++m)
            #pragma unroll
            for (int k = 0; k < 6; ++k)
                ofrag[m][k] = *(const bf16x8*)&XO[(16 * m + lr) * XSTR + k * 32 + lq * 8];
        for (int nt = wave; nt < 12; nt += 4) {
            const bf16* wp = wprojT + (size_t)(nt * 16 + lr) * CDIM + lq * 8;
            bf16x8 bfrag[6];
            #pragma unroll
            for (int k = 0; k < 6; ++k) bfrag[k] = *(const bf16x8*)(wp + k * 32);
            f32x4 acc[4];
            #pragma unroll
            for (int m = 0; m < 4; ++m) acc[m] = f32x4{0.f, 0.f, 0.f, 0.f};
            #pragma unroll
            for (int k = 0; k < 6; ++k)
                #pragma unroll
                for (int m = 0; m < 4; ++m)
                    acc[m] = __builtin_amdgcn_mfma_f32_16x16x32_bf16(ofrag[m][k], bfrag[k], acc[m], 0, 0, 0);
            const int cc   = nt * 16 + lr;
            const float bb = b_proj[cc];
            #pragma unroll
            for (int m = 0; m < 4; ++m)
                #pragma unroll
                for (int r = 0; r < 4; ++r) {
                    int row = 16 * m + lq * 4 + r;
                    if (row < NTOK) {
                        int ty = row / 7, tx = row % 7;
                        int oy = (wy * 7 + ty + SHIFTV) % IMG;
                        int ox = (wx * 7 + tx + SHIFTV) % IMG;
                        out[(((size_t)bimg * IMG + oy) * IMG + ox) * CDIM + cc] = acc[m][r] + bb;
                    }
                }
        }
    }
}

extern "C" void kernel_launch(void* const* d_in, const int* in_sizes, int n_in,
                              void* d_out, int out_size, void* d_ws, size_t ws_size,
                              hipStream_t stream) {
    const float* x           = (const float*)d_in[0];
    const float* gamma       = (const float*)d_in[1];
    const float* beta        = (const float*)d_in[2];
    const float* w_qkv       = (const float*)d_in[3];
    const float* b_qkv       = (const float*)d_in[4];
    const float* rel_table   = (const float*)d_in[5];
    const float* w_proj      = (const float*)d_in[6];
    const float* b_proj      = (const float*)d_in[7];
    const float* mask_matrix = (const float*)d_in[8];
    float* out = (float*)d_out;

    bf16* wqkvT  = (bf16*)d_ws;
    bf16* wprojT = (bf16*)((char*)d_ws + (size_t)576 * 192 * 2);

    prep_weights<<<432, 256, 0, stream>>>(w_qkv, w_proj, wqkvT, wprojT);
    swin_block<<<4096, 256, 0, stream>>>(x, gamma, beta, wqkvT, b_qkv, rel_table,
                                         wprojT, b_proj, mask_matrix, out);
}

// Round 2
// 466.498 us; speedup vs baseline: 1.4503x; 1.4503x over previous
//
#include <hip/hip_runtime.h>
#include <hip/hip_bf16.h>
#include <math.h>

typedef __bf16 bf16;
typedef __bf16 bf16x8 __attribute__((ext_vector_type(8)));
typedef float f32x4 __attribute__((ext_vector_type(4)));

#define NHEADS 6
#define CDIM 192
#define IMG 56
#define NTOK 49
#define SHIFTV 3
#define XSTR 200   // padded row stride (bf16) for BufA/BufB: 400 B
#define VSTR 72    // padded stride for VT / P scratch: 144 B (16B-aligned rows)
#define SCALE 0.17677669529663687f

// ---- weight prep: fp32 -> bf16, transposed to [N][K] so B-fragments are contiguous ----
__global__ void prep_weights(const float* __restrict__ w_qkv, const float* __restrict__ w_proj,
                             bf16* __restrict__ wqkvT, bf16* __restrict__ wprojT) {
    int i = blockIdx.x * 256 + threadIdx.x;
    if (i < 576 * 192) {
        int n = i / 192, k = i % 192;
        wqkvT[i] = (bf16)w_qkv[k * 576 + n];
    }
    if (i < 192 * 192) {
        int n = i / 192, k = i % 192;
        wprojT[i] = (bf16)w_proj[k * 192 + n];
    }
}

__global__ __launch_bounds__(512, 1) void swin_block(
    const float* __restrict__ x, const float* __restrict__ gamma, const float* __restrict__ beta,
    const bf16* __restrict__ wqkvT, const float* __restrict__ b_qkv,
    const float* __restrict__ rel_table, const bf16* __restrict__ wprojT,
    const float* __restrict__ b_proj, float* __restrict__ out)
{
    __shared__ __align__(16) bf16 BufA[64 * XSTR];     // X (ph0-1 reads), then K
    __shared__ __align__(16) bf16 BufB[64 * XSTR];     // Q (ph1-2), then O in-place (ph2-3)
    __shared__ __align__(16) bf16 VTs[CDIM * VSTR];    // V transposed: [channel][token]
    __shared__ __align__(16) bf16 Pws[8 * 16 * VSTR];  // per-wave P scratch
    __shared__ float biasS[169 * NHEADS];

    const int blk  = blockIdx.x;
    const int bimg = blk >> 6;
    const int wy   = (blk >> 3) & 7;
    const int wx   = blk & 7;
    const int tid  = threadIdx.x;
    const int wave = tid >> 6;   // 0..7
    const int lane = tid & 63;

    for (int i = tid; i < 169 * NHEADS; i += 512) biasS[i] = rel_table[i];

    // ---- phase 0: shifted-window load + LayerNorm -> BufA (bf16), rows 49..63 zero ----
    {
        const float g0 = gamma[lane], g1 = gamma[lane + 64], g2 = gamma[lane + 128];
        const float b0 = beta[lane],  b1 = beta[lane + 64],  b2 = beta[lane + 128];
        for (int t = wave; t < 64; t += 8) {
            if (t < NTOK) {
                int ty = t / 7, tx = t % 7;
                int oy = (wy * 7 + ty + SHIFTV) % IMG;
                int ox = (wx * 7 + tx + SHIFTV) % IMG;
                const float* xp = x + (((size_t)bimg * IMG + oy) * IMG + ox) * CDIM;
                float v0 = xp[lane], v1 = xp[lane + 64], v2 = xp[lane + 128];
                float s = v0 + v1 + v2, ss = v0 * v0 + v1 * v1 + v2 * v2;
                #pragma unroll
                for (int off = 32; off; off >>= 1) { s += __shfl_xor(s, off); ss += __shfl_xor(ss, off); }
                float mu  = s * (1.f / 192.f);
                float var = ss * (1.f / 192.f) - mu * mu;
                float rs  = rsqrtf(var + 1e-5f);
                BufA[t * XSTR + lane      ] = (bf16)((v0 - mu) * rs * g0 + b0);
                BufA[t * XSTR + lane + 64 ] = (bf16)((v1 - mu) * rs * g1 + b1);
                BufA[t * XSTR + lane + 128] = (bf16)((v2 - mu) * rs * g2 + b2);
            } else {
                BufA[t * XSTR + lane      ] = (bf16)0.f;
                BufA[t * XSTR + lane + 64 ] = (bf16)0.f;
                BufA[t * XSTR + lane + 128] = (bf16)0.f;
            }
        }
    }
    __syncthreads();

    // ---- phase 1: QKV = X @ Wqkv + b -> Q->BufB, K->BufA (in place over X), V^T->VTs ----
    {
        const int lr = lane & 15, lq = lane >> 4;
        bf16x8 afrag[4][6];
        #pragma unroll
        for (int m = 0; m < 4; ++m)
            #pragma unroll
            for (int k = 0; k < 6; ++k)
                afrag[m][k] = *(const bf16x8*)&BufA[(16 * m + lr) * XSTR + k * 32 + lq * 8];
        __syncthreads();   // everyone finished reading X before K overwrites BufA

        for (int nt = wave; nt < 36; nt += 8) {
            const bf16* wp = wqkvT + (size_t)(nt * 16 + lr) * CDIM + lq * 8;
            bf16x8 bfrag[6];
            #pragma unroll
            for (int k = 0; k < 6; ++k) bfrag[k] = *(const bf16x8*)(wp + k * 32);
            f32x4 acc[4];
            #pragma unroll
            for (int m = 0; m < 4; ++m) acc[m] = f32x4{0.f, 0.f, 0.f, 0.f};
            #pragma unroll
            for (int k = 0; k < 6; ++k)
                #pragma unroll
                for (int m = 0; m < 4; ++m)
                    acc[m] = __builtin_amdgcn_mfma_f32_16x16x32_bf16(afrag[m][k], bfrag[k], acc[m], 0, 0, 0);
            const int col  = nt * 16 + lr;
            const float bb = b_qkv[col];
            const int sect = col / CDIM;   // tile-uniform: 0=Q 1=K 2=V
            const int cc   = col % CDIM;
            #pragma unroll
            for (int m = 0; m < 4; ++m)
                #pragma unroll
                for (int r = 0; r < 4; ++r) {
                    int row = 16 * m + lq * 4 + r;
                    float v = acc[m][r] + bb;
                    if (sect == 0)      BufB[row * XSTR + cc] = (bf16)v;
                    else if (sect == 1) BufA[row * XSTR + cc] = (bf16)v;
                    else                VTs[cc * VSTR + row] = (bf16)v;
                }
        }
    }
    __syncthreads();

    // ---- phase 2: attention; wave = (row-tile m = wave&3, head-group = wave>>2), barrier-free ----
    {
        const int lr = lane & 15, lq = lane >> 4;
        const int m  = wave & 3;
        const int hg = wave >> 2;
        bf16* Pw = &Pws[wave * 16 * VSTR];

        // hoisted per-(r,n): rel-pos index and shift-mask (head-independent)
        int   rp[4][4];
        float msk[4][4];
        #pragma unroll
        for (int r = 0; r < 4; ++r) {
            int i  = 16 * m + lq * 4 + r;
            int ic = i < NTOK ? i : NTOK - 1;
            int iy = ic / 7, ix = ic % 7;
            int ryi = ((wy * 7 + iy) < 49) ? 0 : (((wy * 7 + iy) < 53) ? 1 : 2);
            int rxi = ((wx * 7 + ix) < 49) ? 0 : (((wx * 7 + ix) < 53) ? 1 : 2);
            #pragma unroll
            for (int n = 0; n < 4; ++n) {
                int j = 16 * n + lr;
                if (j < NTOK) {
                    int jy = j / 7, jx = j % 7;
                    rp[r][n] = (iy - jy + 6) * 13 + (ix - jx + 6);
                    int ryj = ((wy * 7 + jy) < 49) ? 0 : (((wy * 7 + jy) < 53) ? 1 : 2);
                    int rxj = ((wx * 7 + jx) < 49) ? 0 : (((wx * 7 + jx) < 53) ? 1 : 2);
                    msk[r][n] = (ryi == ryj && rxi == rxj) ? 0.f : -100.f;
                } else { rp[r][n] = 0; msk[r][n] = -1e30f; }
            }
        }

        for (int hh = 0; hh < 3; ++hh) {
            const int h = hg * 3 + hh;
            bf16x8 aq = *(const bf16x8*)&BufB[(16 * m + lr) * XSTR + h * 32 + lq * 8];
            f32x4 s[4];
            #pragma unroll
            for (int n = 0; n < 4; ++n) {
                bf16x8 bk = *(const bf16x8*)&BufA[(16 * n + lr) * XSTR + h * 32 + lq * 8];
                s[n] = __builtin_amdgcn_mfma_f32_16x16x32_bf16(aq, bk, f32x4{0.f, 0.f, 0.f, 0.f}, 0, 0, 0);
            }
            float p[4][4];
            #pragma unroll
            for (int r = 0; r < 4; ++r) {
                float vmax = -1e30f;
                #pragma unroll
                for (int n = 0; n < 4; ++n) {
                    float v = s[n][r] * SCALE + biasS[rp[r][n] * NHEADS + h] + msk[r][n];
                    p[r][n] = v;
                    vmax = fmaxf(vmax, v);
                }
                #pragma unroll
                for (int off = 1; off < 16; off <<= 1) vmax = fmaxf(vmax, __shfl_xor(vmax, off));
                float sum = 0.f;
                #pragma unroll
                for (int n = 0; n < 4; ++n) {
                    float e = __expf(p[r][n] - vmax);   // invalid j underflow to 0
                    p[r][n] = e; sum += e;
                }
                #pragma unroll
                for (int off = 1; off < 16; off <<= 1) sum += __shfl_xor(sum, off);
                float inv = 1.f / sum;
                #pragma unroll
                for (int n = 0; n < 4; ++n) p[r][n] *= inv;
            }
            // D-layout -> A-layout via wave-private LDS scratch (no barrier needed)
            #pragma unroll
            for (int r = 0; r < 4; ++r)
                #pragma unroll
                for (int n = 0; n < 4; ++n)
                    Pw[(lq * 4 + r) * VSTR + 16 * n + lr] = (bf16)p[r][n];
            // PV
            f32x4 o[2];
            o[0] = f32x4{0.f, 0.f, 0.f, 0.f}; o[1] = f32x4{0.f, 0.f, 0.f, 0.f};
            #pragma unroll
            for (int kk = 0; kk < 2; ++kk) {
                bf16x8 ap = *(const bf16x8*)&Pw[lr * VSTR + kk * 32 + lq * 8];
                #pragma unroll
                for (int n = 0; n < 2; ++n) {
                    bf16x8 bv = *(const bf16x8*)&VTs[(h * 32 + 16 * n + lr) * VSTR + kk * 32 + lq * 8];
                    o[n] = __builtin_amdgcn_mfma_f32_16x16x32_bf16(ap, bv, o[n], 0, 0, 0);
                }
            }
            // O overwrites Q in place (same wave-private (m,h) region)
            #pragma unroll
            for (int n = 0; n < 2; ++n)
                #pragma unroll
                for (int r = 0; r < 4; ++r)
                    BufB[(16 * m + lq * 4 + r) * XSTR + h * 32 + 16 * n + lr] = (bf16)o[n][r];
        }
    }
    __syncthreads();

    // ---- phase 3: proj + bias; units = (col-tile, row-half), 3 per wave ----
    {
        const int lr = lane & 15, lq = lane >> 4;
        const int half = wave & 1;
        bf16x8 ofrag[2][6];
        #pragma unroll
        for (int mm = 0; mm < 2; ++mm)
            #pragma unroll
            for (int k = 0; k < 6; ++k)
                ofrag[mm][k] = *(const bf16x8*)&BufB[(16 * (2 * half + mm) + lr) * XSTR + k * 32 + lq * 8];
        for (int s3 = 0; s3 < 3; ++s3) {
            const int nt = (wave >> 1) + 4 * s3;
            const bf16* wp = wprojT + (size_t)(nt * 16 + lr) * CDIM + lq * 8;
            bf16x8 bfrag[6];
            #pragma unroll
            for (int k = 0; k < 6; ++k) bfrag[k] = *(const bf16x8*)(wp + k * 32);
            f32x4 acc[2];
            acc[0] = f32x4{0.f, 0.f, 0.f, 0.f}; acc[1] = f32x4{0.f, 0.f, 0.f, 0.f};
            #pragma unroll
            for (int k = 0; k < 6; ++k)
                #pragma unroll
                for (int mm = 0; mm < 2; ++mm)
                    acc[mm] = __builtin_amdgcn_mfma_f32_16x16x32_bf16(ofrag[mm][k], bfrag[k], acc[mm], 0, 0, 0);
            const int cc   = nt * 16 + lr;
            const float bb = b_proj[cc];
            #pragma unroll
            for (int mm = 0; mm < 2; ++mm)
                #pragma unroll
                for (int r = 0; r < 4; ++r) {
                    int row = 16 * (2 * half + mm) + lq * 4 + r;
                    if (row < NTOK) {
                        int ty = row / 7, tx = row % 7;
                        int oy = (wy * 7 + ty + SHIFTV) % IMG;
                        int ox = (wx * 7 + tx + SHIFTV) % IMG;
                        out[(((size_t)bimg * IMG + oy) * IMG + ox) * CDIM + cc] = acc[mm][r] + bb;
                    }
                }
        }
    }
}

extern "C" void kernel_launch(void* const* d_in, const int* in_sizes, int n_in,
                              void* d_out, int out_size, void* d_ws, size_t ws_size,
                              hipStream_t stream) {
    const float* x           = (const float*)d_in[0];
    const float* gamma       = (const float*)d_in[1];
    const float* beta        = (const float*)d_in[2];
    const float* w_qkv       = (const float*)d_in[3];
    const float* b_qkv       = (const float*)d_in[4];
    const float* rel_table   = (const float*)d_in[5];
    const float* w_proj      = (const float*)d_in[6];
    const float* b_proj      = (const float*)d_in[7];
    // d_in[8] = mask_matrix: recomputed inline from window coords, not needed
    float* out = (float*)d_out;

    bf16* wqkvT  = (bf16*)d_ws;
    bf16* wprojT = (bf16*)((char*)d_ws + (size_t)576 * 192 * 2);

    prep_weights<<<432, 256, 0, stream>>>(w_qkv, w_proj, wqkvT, wprojT);
    swin_block<<<4096, 512, 0, stream>>>(x, gamma, beta, wqkvT, b_qkv, rel_table,
                                         wprojT, b_proj, out);
}

// Round 3
// 372.050 us; speedup vs baseline: 1.8184x; 1.2539x over previous
//
#include <hip/hip_runtime.h>
#include <hip/hip_bf16.h>
#include <math.h>

typedef __bf16 bf16;
typedef __bf16 bf16x4 __attribute__((ext_vector_type(4)));
typedef __bf16 bf16x8 __attribute__((ext_vector_type(8)));
typedef float f32x4 __attribute__((ext_vector_type(4)));
typedef unsigned int u32x4 __attribute__((ext_vector_type(4)));

#define NHEADS 6
#define CDIM 192
#define IMG 56
#define NTOK 49
#define SHIFTV 3
#define XSTR 200   // padded row stride (bf16) for BufA/BufB: 400 B
#define VSTR 72    // padded stride for VT: 144 B (16B-aligned rows)
#define SCALE 0.17677669529663687f

static __device__ __forceinline__ unsigned pack2bf(float lo, float hi) {
    unsigned short a = __builtin_bit_cast(unsigned short, (bf16)lo);
    unsigned short b = __builtin_bit_cast(unsigned short, (bf16)hi);
    return (unsigned)a | ((unsigned)b << 16);
}

// ---- weight prep: fp32 -> bf16, transposed to [N][K] so B-fragments are contiguous ----
__global__ void prep_weights(const float* __restrict__ w_qkv, const float* __restrict__ w_proj,
                             bf16* __restrict__ wqkvT, bf16* __restrict__ wprojT) {
    int i = blockIdx.x * 256 + threadIdx.x;
    if (i < 576 * 192) {
        int n = i / 192, k = i % 192;
        wqkvT[i] = (bf16)w_qkv[k * 576 + n];
    }
    if (i < 192 * 192) {
        int n = i / 192, k = i % 192;
        wprojT[i] = (bf16)w_proj[k * 192 + n];
    }
}

__global__ __launch_bounds__(512, 4) void swin_block(
    const float* __restrict__ x, const float* __restrict__ gamma, const float* __restrict__ beta,
    const bf16* __restrict__ wqkvT, const float* __restrict__ b_qkv,
    const float* __restrict__ rel_table, const bf16* __restrict__ wprojT,
    const float* __restrict__ b_proj, float* __restrict__ out)
{
    __shared__ __align__(16) bf16 BufA[64 * XSTR];     // X (ph0-1), then K (in place)
    __shared__ __align__(16) bf16 BufB[64 * XSTR];     // Q (ph1-2), then O in place (ph2-3)
    __shared__ __align__(16) bf16 VTs[CDIM * VSTR];    // V transposed: [channel][token]
    __shared__ bf16 biasS[169 * NHEADS];               // rel-pos bias, bf16
    // total: 25600+25600+27648+2028 = 80876 B  (<= 81920 -> 2 blocks/CU)

    const int blk  = blockIdx.x;
    const int bimg = blk >> 6;
    const int wy   = (blk >> 3) & 7;
    const int wx   = blk & 7;
    const int tid  = threadIdx.x;
    const int wave = tid >> 6;   // 0..7
    const int lane = tid & 63;

    for (int i = tid; i < 169 * NHEADS; i += 512) biasS[i] = (bf16)rel_table[i];

    // ---- phase 0: shifted-window load + LayerNorm -> BufA (bf16), rows 49..63 zero ----
    {
        const float g0 = gamma[lane], g1 = gamma[lane + 64], g2 = gamma[lane + 128];
        const float b0 = beta[lane],  b1 = beta[lane + 64],  b2 = beta[lane + 128];
        for (int t = wave; t < 64; t += 8) {
            if (t < NTOK) {
                int ty = t / 7, tx = t % 7;
                int oy = (wy * 7 + ty + SHIFTV) % IMG;
                int ox = (wx * 7 + tx + SHIFTV) % IMG;
                const float* xp = x + (((size_t)bimg * IMG + oy) * IMG + ox) * CDIM;
                float v0 = xp[lane], v1 = xp[lane + 64], v2 = xp[lane + 128];
                float s = v0 + v1 + v2, ss = v0 * v0 + v1 * v1 + v2 * v2;
                #pragma unroll
                for (int off = 32; off; off >>= 1) { s += __shfl_xor(s, off); ss += __shfl_xor(ss, off); }
                float mu  = s * (1.f / 192.f);
                float var = ss * (1.f / 192.f) - mu * mu;
                float rs  = rsqrtf(var + 1e-5f);
                BufA[t * XSTR + lane      ] = (bf16)((v0 - mu) * rs * g0 + b0);
                BufA[t * XSTR + lane + 64 ] = (bf16)((v1 - mu) * rs * g1 + b1);
                BufA[t * XSTR + lane + 128] = (bf16)((v2 - mu) * rs * g2 + b2);
            } else {
                BufA[t * XSTR + lane      ] = (bf16)0.f;
                BufA[t * XSTR + lane + 64 ] = (bf16)0.f;
                BufA[t * XSTR + lane + 128] = (bf16)0.f;
            }
        }
    }
    __syncthreads();

    // ---- phase 1: QKV = X @ Wqkv + b. Wave owns row-half (w&1) x col-group (w>>1): 9 tiles, 108 MFMA ----
    {
        const int lr = lane & 15, lq = lane >> 4;
        const int h0 = wave & 1;       // row-half: rows 32*h0 .. 32*h0+31
        const int cg = wave >> 1;      // col-group 0..3
        bf16x8 afrag[2][6];            // 48 VGPR: X rows of our half
        #pragma unroll
        for (int mm = 0; mm < 2; ++mm)
            #pragma unroll
            for (int k = 0; k < 6; ++k)
                afrag[mm][k] = *(const bf16x8*)&BufA[(32 * h0 + 16 * mm + lr) * XSTR + k * 32 + lq * 8];
        __syncthreads();   // all waves cached X before K overwrites BufA

        for (int t = 0; t < 9; ++t) {
            const int nt = cg + 4 * t;
            const bf16* wp = wqkvT + (size_t)(nt * 16 + lr) * CDIM + lq * 8;
            bf16x8 bfrag[6];
            #pragma unroll
            for (int k = 0; k < 6; ++k) bfrag[k] = *(const bf16x8*)(wp + k * 32);
            f32x4 acc[2];
            acc[0] = f32x4{0.f, 0.f, 0.f, 0.f}; acc[1] = f32x4{0.f, 0.f, 0.f, 0.f};
            #pragma unroll
            for (int k = 0; k < 6; ++k)
                #pragma unroll
                for (int mm = 0; mm < 2; ++mm)
                    acc[mm] = __builtin_amdgcn_mfma_f32_16x16x32_bf16(afrag[mm][k], bfrag[k], acc[mm], 0, 0, 0);
            const int col  = nt * 16 + lr;
            const float bb = b_qkv[col];
            const int sect = col / CDIM;   // tile-uniform: 0=Q 1=K 2=V
            const int cc   = col % CDIM;
            if (sect == 2) {
                #pragma unroll
                for (int mm = 0; mm < 2; ++mm) {
                    bf16x4 v4;
                    #pragma unroll
                    for (int r = 0; r < 4; ++r) v4[r] = (bf16)(acc[mm][r] + bb);
                    *(bf16x4*)&VTs[cc * VSTR + 32 * h0 + 16 * mm + 4 * lq] = v4;
                }
            } else {
                bf16* dst = sect ? BufA : BufB;
                #pragma unroll
                for (int mm = 0; mm < 2; ++mm)
                    #pragma unroll
                    for (int r = 0; r < 4; ++r)
                        dst[(32 * h0 + 16 * mm + 4 * lq + r) * XSTR + cc] = (bf16)(acc[mm][r] + bb);
            }
        }
    }
    __syncthreads();

    // ---- phase 2: attention, swapped operands (S^T), in-register P^T, barrier-free ----
    {
        const int li = lane & 15, lq = lane >> 4;
        const int m  = wave & 3;
        const int hg = wave >> 2;
        const int i  = 16 * m + li;              // query token (fixed per lane)
        const int ic = i < NTOK ? i : NTOK - 1;
        const int iy = ic / 7, ix = ic % 7;
        const int ay = wy * 7 + iy, ax = wx * 7 + ix;
        const int ryi = (ay < 49) ? 0 : ((ay < 53) ? 1 : 2);
        const int rxi = (ax < 49) ? 0 : ((ax < 53) ? 1 : 2);
        int   rp[4][4];
        float msk[4][4];
        #pragma unroll
        for (int n = 0; n < 4; ++n)
            #pragma unroll
            for (int r = 0; r < 4; ++r) {
                int j = 16 * n + 4 * lq + r;     // key token
                if (j < NTOK) {
                    int jy = j / 7, jx = j % 7;
                    rp[n][r] = ((iy - jy + 6) * 13 + (ix - jx + 6)) * NHEADS;
                    int by = wy * 7 + jy, bx = wx * 7 + jx;
                    int ryj = (by < 49) ? 0 : ((by < 53) ? 1 : 2);
                    int rxj = (bx < 49) ? 0 : ((bx < 53) ? 1 : 2);
                    msk[n][r] = (ryi == ryj && rxi == rxj) ? 0.f : -100.f;
                } else { rp[n][r] = 0; msk[n][r] = -1e30f; }
            }
        const int src0 = li + 32 * (lq & 1);

        for (int hh = 0; hh < 3; ++hh) {
            const int h = hg * 3 + hh;
            bf16x8 bq = *(const bf16x8*)&BufB[(16 * m + li) * XSTR + h * 32 + lq * 8];
            f32x4 st[4];
            #pragma unroll
            for (int n = 0; n < 4; ++n) {
                bf16x8 ak = *(const bf16x8*)&BufA[(16 * n + li) * XSTR + h * 32 + lq * 8];
                st[n] = __builtin_amdgcn_mfma_f32_16x16x32_bf16(ak, bq, f32x4{0.f, 0.f, 0.f, 0.f}, 0, 0, 0);
            }
            // S^T: lane holds S[i][j], j = 16n + 4lq + r
            float p[4][4];
            float vmax = -1e30f;
            #pragma unroll
            for (int n = 0; n < 4; ++n)
                #pragma unroll
                for (int r = 0; r < 4; ++r) {
                    float v = st[n][r] * SCALE + (float)biasS[rp[n][r] + h] + msk[n][r];
                    p[n][r] = v;
                    vmax = fmaxf(vmax, v);
                }
            vmax = fmaxf(vmax, __shfl_xor(vmax, 16));
            vmax = fmaxf(vmax, __shfl_xor(vmax, 32));
            float sum = 0.f;
            #pragma unroll
            for (int n = 0; n < 4; ++n)
                #pragma unroll
                for (int r = 0; r < 4; ++r) {
                    float e = __expf(p[n][r] - vmax);
                    p[n][r] = e; sum += e;
                }
            sum += __shfl_xor(sum, 16);
            sum += __shfl_xor(sum, 32);
            const float inv = 1.f / sum;
            // pack normalized P to bf16 pairs: pk[n][s] = {p[n][2s], p[n][2s+1]}
            unsigned pk[4][2];
            #pragma unroll
            for (int n = 0; n < 4; ++n)
                #pragma unroll
                for (int s = 0; s < 2; ++s)
                    pk[n][s] = pack2bf(p[n][2 * s] * inv, p[n][2 * s + 1] * inv);
            // shuffle D-layout -> B-frag(P^T): elem e of chunk kk = p[2kk+(lq>>1)][e&3] from lane src0+16*(e>>2)
            u32x4 ptw0, ptw1;
            #pragma unroll
            for (int w = 0; w < 4; ++w) {
                int srcl = src0 + 16 * (w >> 1);
                int s = w & 1;
                unsigned a0 = (unsigned)__shfl((int)pk[0][s], srcl);
                unsigned b0 = (unsigned)__shfl((int)pk[1][s], srcl);
                unsigned a1 = (unsigned)__shfl((int)pk[2][s], srcl);
                unsigned b1 = (unsigned)__shfl((int)pk[3][s], srcl);
                ptw0[w] = (lq & 2) ? b0 : a0;
                ptw1[w] = (lq & 2) ? b1 : a1;
            }
            bf16x8 bp0 = __builtin_bit_cast(bf16x8, ptw0);
            bf16x8 bp1 = __builtin_bit_cast(bf16x8, ptw1);
            // PV: O^T = V^T · P^T
            f32x4 ot[2];
            #pragma unroll
            for (int dt = 0; dt < 2; ++dt) {
                const bf16* vrow = &VTs[(h * 32 + 16 * dt + li) * VSTR + lq * 8];
                bf16x8 av0 = *(const bf16x8*)(vrow);
                bf16x8 av1 = *(const bf16x8*)(vrow + 32);
                ot[dt] = __builtin_amdgcn_mfma_f32_16x16x32_bf16(av0, bp0, f32x4{0.f, 0.f, 0.f, 0.f}, 0, 0, 0);
                ot[dt] = __builtin_amdgcn_mfma_f32_16x16x32_bf16(av1, bp1, ot[dt], 0, 0, 0);
            }
            // O^T[d][i] -> BufB[i][d] (over Q, wave-private region), packed 8B stores
            #pragma unroll
            for (int dt = 0; dt < 2; ++dt) {
                bf16x4 o4;
                #pragma unroll
                for (int r = 0; r < 4; ++r) o4[r] = (bf16)ot[dt][r];
                *(bf16x4*)&BufB[(16 * m + li) * XSTR + h * 32 + 16 * dt + 4 * lq] = o4;
            }
        }
    }
    __syncthreads();

    // ---- phase 3: proj + bias; units = (col-tile, row-half), 3 per wave ----
    {
        const int lr = lane & 15, lq = lane >> 4;
        const int half = wave & 1;
        bf16x8 ofrag[2][6];
        #pragma unroll
        for (int mm = 0; mm < 2; ++mm)
            #pragma unroll
            for (int k = 0; k < 6; ++k)
                ofrag[mm][k] = *(const bf16x8*)&BufB[(16 * (2 * half + mm) + lr) * XSTR + k * 32 + lq * 8];
        for (int s3 = 0; s3 < 3; ++s3) {
            const int nt = (wave >> 1) + 4 * s3;
            const bf16* wp = wprojT + (size_t)(nt * 16 + lr) * CDIM + lq * 8;
            bf16x8 bfrag[6];
            #pragma unroll
            for (int k = 0; k < 6; ++k) bfrag[k] = *(const bf16x8*)(wp + k * 32);
            f32x4 acc[2];
            acc[0] = f32x4{0.f, 0.f, 0.f, 0.f}; acc[1] = f32x4{0.f, 0.f, 0.f, 0.f};
            #pragma unroll
            for (int k = 0; k < 6; ++k)
                #pragma unroll
                for (int mm = 0; mm < 2; ++mm)
                    acc[mm] = __builtin_amdgcn_mfma_f32_16x16x32_bf16(ofrag[mm][k], bfrag[k], acc[mm], 0, 0, 0);
            const int cc   = nt * 16 + lr;
            const float bb = b_proj[cc];
            #pragma unroll
            for (int mm = 0; mm < 2; ++mm)
                #pragma unroll
                for (int r = 0; r < 4; ++r) {
                    int row = 16 * (2 * half + mm) + lq * 4 + r;
                    if (row < NTOK) {
                        int ty = row / 7, tx = row % 7;
                        int oy = (wy * 7 + ty + SHIFTV) % IMG;
                        int ox = (wx * 7 + tx + SHIFTV) % IMG;
                        out[(((size_t)bimg * IMG + oy) * IMG + ox) * CDIM + cc] = acc[mm][r] + bb;
                    }
                }
        }
    }
}

extern "C" void kernel_launch(void* const* d_in, const int* in_sizes, int n_in,
                              void* d_out, int out_size, void* d_ws, size_t ws_size,
                              hipStream_t stream) {
    const float* x           = (const float*)d_in[0];
    const float* gamma       = (const float*)d_in[1];
    const float* beta        = (const float*)d_in[2];
    const float* w_qkv       = (const float*)d_in[3];
    const float* b_qkv       = (const float*)d_in[4];
    const float* rel_table   = (const float*)d_in[5];
    const float* w_proj      = (const float*)d_in[6];
    const float* b_proj      = (const float*)d_in[7];
    // d_in[8] = mask_matrix: recomputed inline from window coords, not needed
    float* out = (float*)d_out;

    bf16* wqkvT  = (bf16*)d_ws;
    bf16* wprojT = (bf16*)((char*)d_ws + (size_t)576 * 192 * 2);

    prep_weights<<<432, 256, 0, stream>>>(w_qkv, w_proj, wqkvT, wprojT);
    swin_block<<<4096, 512, 0, stream>>>(x, gamma, beta, wqkvT, b_qkv, rel_table,
                                         wprojT, b_proj, out);
}